// Round 6
// baseline (34.987 us; speedup 1.0000x reference)
//
#include <hip/hip_runtime.h>
#include <hip/hip_bf16.h>
#include <math.h>

// Problem constants (fixed by the reference's setup_inputs)
#define N_STATE 1024
#define N_HEAD  16
#define H_DIM   64          // N_STATE / N_HEAD
#define NUM_ROT 8
#define SEQ     4096

typedef __attribute__((ext_vector_type(8))) short bf16x8;
typedef __attribute__((ext_vector_type(4))) float f32x4;

// float -> bf16 (round-to-nearest-even)
__device__ __forceinline__ unsigned short f2bf(float f) {
    union { float f; unsigned u; } v; v.f = f;
    unsigned r = v.u + 0x7fffu + ((v.u >> 16) & 1u);
    return (unsigned short)(r >> 16);
}

// ---------------------------------------------------------------------------
// Kernel 1: compose R = G_0 @ ... @ G_7 @ rotation_matrix; emit R^T in bf16
// with PERMUTED feature rows: row p = (f&1)*32 + (f>>1) holds R^T row f.
// So the MFMA output y' = [y_even | y_odd] -> RoPE x1/x2 are acc-tile pairs
// and output columns are contiguous per lane (enables direct float4 stores).
// ---------------------------------------------------------------------------
__global__ __launch_bounds__(256)
void compose_R_kernel(const float* __restrict__ thetas,
                      const float* __restrict__ pairs,
                      const float* __restrict__ theta_scale,
                      const float* __restrict__ M,
                      unsigned short* __restrict__ Rt)   // bf16 [64 p][64 k]
{
    __shared__ float R[H_DIM * H_DIM];
    __shared__ float Ms[H_DIM * H_DIM];
    __shared__ float th_s[NUM_ROT];
    __shared__ int   pr_s[2 * NUM_ROT];

    const int t = threadIdx.x;

    if (t < NUM_ROT)      th_s[t] = thetas[t] * theta_scale[0];
    if (t < 2 * NUM_ROT)  pr_s[t] = (int)pairs[t];

    {
        const float4* Mg = reinterpret_cast<const float4*>(M);
        float4* Ms4 = reinterpret_cast<float4*>(Ms);
        #pragma unroll
        for (int q = 0; q < 4; ++q)
            Ms4[t + q * 256] = Mg[t + q * 256];
    }
    {
        float4* R4 = reinterpret_cast<float4*>(R);
        #pragma unroll
        for (int q = 0; q < 4; ++q) {
            const int idx = t + q * 256;
            const int row = idx >> 4;
            const int c0  = (idx & 15) * 4;
            float4 v;
            v.x = (row == c0    ) ? 1.0f : 0.0f;
            v.y = (row == c0 + 1) ? 1.0f : 0.0f;
            v.z = (row == c0 + 2) ? 1.0f : 0.0f;
            v.w = (row == c0 + 3) ? 1.0f : 0.0f;
            R4[idx] = v;
        }
    }
    __syncthreads();

    for (int k = 0; k < NUM_ROT; ++k) {
        const int i = pr_s[2 * k];
        const int j = pr_s[2 * k + 1];
        float sth, cth;
        sincosf(th_s[k], &sth, &cth);
        if (t < H_DIM) {
            const float ri = R[t * H_DIM + i];
            const float rj = R[t * H_DIM + j];
            if (i == j) {
                R[t * H_DIM + i] = cth * ri;
            } else {
                R[t * H_DIM + i] =  cth * ri + sth * rj;
                R[t * H_DIM + j] = -sth * ri + cth * rj;
            }
        }
        __syncthreads();
    }

    // Rfinal = R @ Ms ; store transposed bf16 with feature permutation
    const int r  = t >> 2;
    const int c0 = (t & 3) * 16;
    float acc[16];
    #pragma unroll
    for (int c = 0; c < 16; ++c) acc[c] = 0.0f;

    #pragma unroll 8
    for (int kk = 0; kk < H_DIM; ++kk) {
        const float a = R[r * H_DIM + kk];
        const float4* mrow = reinterpret_cast<const float4*>(&Ms[kk * H_DIM + c0]);
        #pragma unroll
        for (int c4 = 0; c4 < 4; ++c4) {
            const float4 m = mrow[c4];
            acc[c4 * 4 + 0] = fmaf(a, m.x, acc[c4 * 4 + 0]);
            acc[c4 * 4 + 1] = fmaf(a, m.y, acc[c4 * 4 + 1]);
            acc[c4 * 4 + 2] = fmaf(a, m.z, acc[c4 * 4 + 2]);
            acc[c4 * 4 + 3] = fmaf(a, m.w, acc[c4 * 4 + 3]);
        }
    }
    #pragma unroll
    for (int c = 0; c < 16; ++c) {
        const int f = c0 + c;
        const int p = ((f & 1) << 5) | (f >> 1);   // [evens | odds] permutation
        Rt[p * H_DIM + r] = f2bf(acc[c]);
    }
}

// ---------------------------------------------------------------------------
// Kernel 2: MFMA main kernel, LDS-op-minimized.
//  - Rt staged via b128 (2/thread), A-frags from LDS (stride-72: 2-way, free)
//  - x: wave-contiguous loads -> bf16 -> wave-private LDS -> B-frags
//  - output: permuted-feature acc => 4 consecutive out cols per acc tile;
//    RoPE mixes acc pairs (0,2),(1,3) in-register; DIRECT float4 stores,
//    each wave instr covering 16 full 64B lines. No output LDS round-trip.
// ---------------------------------------------------------------------------
#define HVPB 128
#define XS_STRIDE 72   // shorts per staged row (144 B: 16B-aligned, 2-way banks)

__global__ __launch_bounds__(256)
void rope_mfma_kernel(const float* __restrict__ x,
                      const unsigned short* __restrict__ Rt,  // bf16 [64][64]
                      const float* __restrict__ inv_freq,
                      float* __restrict__ out)
{
    __shared__ unsigned short Rs[H_DIM * XS_STRIDE];          // 9216 B
    __shared__ float snc[8 * 64];                             // 2048 B
    __shared__ __align__(16) unsigned short xs[4][16 * XS_STRIDE]; // 4 x 2304 B

    const int t   = threadIdx.x;
    const int w   = t >> 6;
    const int l   = t & 63;
    const int r16 = l & 15;
    const int q4  = l >> 4;
    const long long hv_base = (long long)blockIdx.x * HVPB;

    // --- stage Rt -> Rs: 512 x 16B chunks, 2 per thread, coalesced b128 ---
    {
        const uint4* Rg = reinterpret_cast<const uint4*>(Rt);
        #pragma unroll
        for (int i = 0; i < 2; ++i) {
            const int c  = t + i * 256;      // 0..511
            const int m  = c >> 3;           // row 0..63
            const int k8 = c & 7;            // 16B chunk in row
            *reinterpret_cast<uint4*>(&Rs[m * XS_STRIDE + k8 * 8]) = Rg[c];
        }
    }

    // --- sin/cos for this block's 8 positions ---
    {
        const int rl = t >> 5;
        const int f  = t & 31;
        const int pos = (int)(((hv_base >> 4) + rl) & (SEQ - 1));
        float sv, cv;
        sincosf((float)pos * inv_freq[f], &sv, &cv);
        snc[rl * 64 + f]      = sv;
        snc[rl * 64 + 32 + f] = cv;
    }
    __syncthreads();

    // --- A frags from Rs (rows = permuted features) ---
    bf16x8 afr[4][2];
    #pragma unroll
    for (int mt = 0; mt < 4; ++mt)
        #pragma unroll
        for (int kh = 0; kh < 2; ++kh)
            afr[mt][kh] = *reinterpret_cast<const bf16x8*>(
                &Rs[(mt * 16 + r16) * XS_STRIDE + kh * 32 + q4 * 8]);

    unsigned short* xw = &xs[w][0];

    #pragma unroll
    for (int nt = 0; nt < 2; ++nt) {
        const size_t row0 = (size_t)(hv_base + w * 32 + nt * 16);

        // --- load 16 rows (4KiB) wave-contiguous, cvt bf16, stage ---
        {
            const float4* xg = reinterpret_cast<const float4*>(x + row0 * H_DIM);
            #pragma unroll
            for (int i = 0; i < 4; ++i) {
                const int flat = i * 64 + l;     // float4 chunk 0..255
                const float4 v = xg[flat];
                const int row = flat >> 4;       // 0..15
                const int c4  = flat & 15;
                ushort4 b;
                b.x = f2bf(v.x); b.y = f2bf(v.y);
                b.z = f2bf(v.z); b.w = f2bf(v.w);
                *reinterpret_cast<ushort4*>(&xw[row * XS_STRIDE + c4 * 4]) = b;
            }
        }

        // --- B frags + MFMA (wave-private; lgkmcnt ordering) ---
        f32x4 acc[4];
        {
            bf16x8 b0 = *reinterpret_cast<const bf16x8*>(&xw[r16 * XS_STRIDE + 0 * 32 + q4 * 8]);
            bf16x8 b1 = *reinterpret_cast<const bf16x8*>(&xw[r16 * XS_STRIDE + 1 * 32 + q4 * 8]);
            #pragma unroll
            for (int mt = 0; mt < 4; ++mt) {
                f32x4 z = {0.0f, 0.0f, 0.0f, 0.0f};
                z = __builtin_amdgcn_mfma_f32_16x16x32_bf16(afr[mt][0], b0, z, 0, 0, 0);
                z = __builtin_amdgcn_mfma_f32_16x16x32_bf16(afr[mt][1], b1, z, 0, 0, 0);
                acc[mt] = z;
            }
        }

        // --- RoPE in-register (acc tiles: 0,1 = x1 cols p; 2,3 = x2 cols p) ---
        // out[row][p]    = x1[p]*cos[p] - x2[p]*sin[p]
        // out[row][32+p] = x1[p]*sin[p] + x2[p]*cos[p]
        const int pl = w * 2 + nt;
        float* op = out + row0 * H_DIM + (size_t)r16 * H_DIM;

        #pragma unroll
        for (int half = 0; half < 2; ++half) {           // acc pair (half, half+2)
            const int p0 = half * 16 + q4 * 4;           // 4 consecutive cols
            const float4 sn = *reinterpret_cast<const float4*>(&snc[pl * 64 + p0]);
            const float4 cs = *reinterpret_cast<const float4*>(&snc[pl * 64 + 32 + p0]);
            const f32x4 a1 = acc[half];
            const f32x4 a2 = acc[half + 2];
            float4 olo, ohi;
            olo.x = a1.x * cs.x - a2.x * sn.x;
            olo.y = a1.y * cs.y - a2.y * sn.y;
            olo.z = a1.z * cs.z - a2.z * sn.z;
            olo.w = a1.w * cs.w - a2.w * sn.w;
            ohi.x = a1.x * sn.x + a2.x * cs.x;
            ohi.y = a1.y * sn.y + a2.y * cs.y;
            ohi.z = a1.z * sn.z + a2.z * cs.z;
            ohi.w = a1.w * sn.w + a2.w * cs.w;
            *reinterpret_cast<float4*>(op + p0)      = olo;   // cols p0..p0+3
            *reinterpret_cast<float4*>(op + 32 + p0) = ohi;   // cols 32+p0..
        }
    }
}

// ---------------------------------------------------------------------------
extern "C" void kernel_launch(void* const* d_in, const int* in_sizes, int n_in,
                              void* d_out, int out_size, void* d_ws, size_t ws_size,
                              hipStream_t stream)
{
    const float* x      = (const float*)d_in[0];
    const float* thetas = (const float*)d_in[1];
    const float* pairs  = (const float*)d_in[2];
    const float* tscale = (const float*)d_in[3];
    const float* M      = (const float*)d_in[4];
    const float* invf   = (const float*)d_in[5];
    float* out = (float*)d_out;
    unsigned short* Rt = (unsigned short*)d_ws;   // bf16 permuted R^T, 8 KiB

    compose_R_kernel<<<1, 256, 0, stream>>>(thetas, pairs, tscale, M, Rt);

    const int n_hv   = in_sizes[0] / H_DIM;     // B*S*N_HEAD = 262144
    const int blocks = n_hv / HVPB;              // 2048
    rope_mfma_kernel<<<blocks, 256, 0, stream>>>(x, Rt, invf, out);
}

// Round 7
// 32.813 us; speedup vs baseline: 1.0663x; 1.0663x over previous
//
#include <hip/hip_runtime.h>
#include <hip/hip_bf16.h>
#include <math.h>

// Problem constants (fixed by the reference's setup_inputs)
#define N_STATE 1024
#define N_HEAD  16
#define H_DIM   64          // N_STATE / N_HEAD
#define NUM_ROT 8
#define SEQ     4096
#define HVPB    128

typedef __attribute__((ext_vector_type(8))) short bf16x8;
typedef __attribute__((ext_vector_type(4))) float f32x4;

// float -> bf16 (round-to-nearest-even)
__device__ __forceinline__ unsigned short f2bf(float f) {
    union { float f; unsigned u; } v; v.f = f;
    unsigned r = v.u + 0x7fffu + ((v.u >> 16) & 1u);
    return (unsigned short)(r >> 16);
}

#define RF_STRIDE 68   // floats per row of Rf/Ms (64 + 4 pad)
#define RT_STRIDE 72   // shorts per row of Rt_s / xs
// Static LDS layout (bytes):
//   [0      .. 17408) Rf   fp32 [64][68]  compose only | overlay: snc [0,2048) + xs [2048,11264)
//   [17408  .. 34816) Ms   fp32 [64][68]  compose only
//   [34816  .. 44032) Rt_s bf16 [64][72]  live whole kernel (permuted R^T)
//   [44032  .. 44096) csh  8 x (cos,sin)
//   [44096  .. 44160) prs  16 ints
#define SM_TOTAL 44160

// ---------------------------------------------------------------------------
// Single fused kernel. Phases:
//  A) compose (redundant per block): stage M, Givens (row-local, barrier-free),
//     R@M via 8 bf16 MFMAs (idle matrix pipe; 0.45us chip-wide total),
//     write permuted bf16 R^T to LDS. Kills the 1-block serial kernel + gap.
//  B) main (identical to round 6): x wave-contiguous -> bf16 -> wave-private
//     LDS -> B-frags; MFMA; in-register RoPE (permuted features => direct
//     full-line float4 stores).
// ---------------------------------------------------------------------------
__global__ __launch_bounds__(256)
void rope_fused_kernel(const float* __restrict__ x,
                       const float* __restrict__ thetas,
                       const float* __restrict__ pairs,
                       const float* __restrict__ theta_scale,
                       const float* __restrict__ M,
                       const float* __restrict__ inv_freq,
                       float* __restrict__ out)
{
    __shared__ __align__(16) char smem[SM_TOTAL];
    float*          Rf   = (float*)(smem);
    float*          Ms   = (float*)(smem + 17408);
    unsigned short* Rt_s = (unsigned short*)(smem + 34816);
    float*          csh  = (float*)(smem + 44032);
    int*            prs  = (int*)(smem + 44096);
    float*          snc  = (float*)(smem);                    // overlay
    unsigned short* xs   = (unsigned short*)(smem + 2048);    // overlay

    const int t   = threadIdx.x;
    const int w   = t >> 6;
    const int l   = t & 63;
    const int r16 = l & 15;
    const int q4  = l >> 4;
    const long long hv_base = (long long)blockIdx.x * HVPB;

    // ===================== phase A: compose =====================
    // stage M -> Ms (stride-68), coalesced float4
    {
        const float4* Mg = (const float4*)M;
        #pragma unroll
        for (int q = 0; q < 4; ++q) {
            const int c   = t + q * 256;      // float4 chunk 0..1023
            const int row = c >> 4;
            const int c4  = c & 15;
            *(float4*)&Ms[row * RF_STRIDE + c4 * 4] = Mg[c];
        }
    }
    // zero Rf (4352 floats = 17/thread)
    #pragma unroll
    for (int q = 0; q < 17; ++q) Rf[t + q * 256] = 0.0f;
    // small params
    if (t < NUM_ROT) {
        float sv, cv;
        sincosf(thetas[t] * theta_scale[0], &sv, &cv);
        csh[2 * t] = cv; csh[2 * t + 1] = sv;
    }
    if (t < 2 * NUM_ROT) prs[t] = (int)pairs[t];
    __syncthreads();

    // Givens rotations: R = G_0..G_7 applied as column ops — each row evolves
    // independently (row-local reads/writes) => no barriers in the loop.
    if (t < H_DIM) {
        float* myrow = &Rf[t * RF_STRIDE];
        myrow[t] = 1.0f;
        #pragma unroll
        for (int k = 0; k < NUM_ROT; ++k) {
            const int   i = prs[2 * k], j = prs[2 * k + 1];
            const float c = csh[2 * k], s = csh[2 * k + 1];
            const float ri = myrow[i], rj = myrow[j];
            if (i == j) {
                myrow[i] = c * ri;                    // chained .at corner case
            } else {
                myrow[i] =  c * ri + s * rj;
                myrow[j] = -s * ri + c * rj;
            }
        }
    }
    __syncthreads();

    // compose-GEMM on the matrix pipe: D = M^T (A) x R^T (B) = final^T.
    // Wave w computes D rows f in [w*16, w*16+16), all 64 cols.
    {
        // A-frags: A[f][k2] = Ms[k2][f] (column reads of Ms)
        bf16x8 ca[2];
        #pragma unroll
        for (int kh = 0; kh < 2; ++kh) {
            const int k2b = kh * 32 + q4 * 8;
            const int f   = w * 16 + r16;
            bf16x8 a;
            #pragma unroll
            for (int e = 0; e < 8; ++e)
                a[e] = (short)f2bf(Ms[(k2b + e) * RF_STRIDE + f]);
            ca[kh] = a;
        }
        // B-frags: row (j*16+r16) of Rf, consecutive k2; MFMA-accumulate
        f32x4 dacc[4];
        #pragma unroll
        for (int j = 0; j < 4; ++j) {
            f32x4 z = {0.f, 0.f, 0.f, 0.f};
            #pragma unroll
            for (int kh = 0; kh < 2; ++kh) {
                const float* rp = &Rf[(j * 16 + r16) * RF_STRIDE + kh * 32 + q4 * 8];
                const float4 f0 = *(const float4*)(rp);
                const float4 f1 = *(const float4*)(rp + 4);
                bf16x8 b;
                b[0] = (short)f2bf(f0.x); b[1] = (short)f2bf(f0.y);
                b[2] = (short)f2bf(f0.z); b[3] = (short)f2bf(f0.w);
                b[4] = (short)f2bf(f1.x); b[5] = (short)f2bf(f1.y);
                b[6] = (short)f2bf(f1.z); b[7] = (short)f2bf(f1.w);
                z = __builtin_amdgcn_mfma_f32_16x16x32_bf16(ca[kh], b, z, 0, 0, 0);
            }
            dacc[j] = z;
        }
        // D[f][k] -> Rt_s[p][k], p = (f&1)*32 + f>>1  ([evens|odds] perm)
        #pragma unroll
        for (int j = 0; j < 4; ++j) {
            #pragma unroll
            for (int r = 0; r < 4; ++r) {
                const int f = w * 16 + q4 * 4 + r;       // D row (C/D layout)
                const int p = ((f & 1) << 5) | (f >> 1);
                Rt_s[p * RT_STRIDE + j * 16 + r16] = f2bf(dacc[j][r]);
            }
        }
    }

    // sin/cos VALU part before the barrier (regs), LDS write after
    const int srl = t >> 5;          // 0..7
    const int sf  = t & 31;          // 0..31
    float sv_, cv_;
    {
        const int pos = (int)(((hv_base >> 4) + srl) & (SEQ - 1));
        sincosf((float)pos * inv_freq[sf], &sv_, &cv_);
    }
    __syncthreads();                 // Rt_s complete; Rf/Ms dead => overlay ok

    // ===================== phase B: main (as round 6) =====================
    snc[srl * 64 + sf]      = sv_;
    snc[srl * 64 + 32 + sf] = cv_;

    // A-frags from Rt_s (written pre-barrier)
    bf16x8 afr[4][2];
    #pragma unroll
    for (int mt = 0; mt < 4; ++mt)
        #pragma unroll
        for (int kh = 0; kh < 2; ++kh)
            afr[mt][kh] = *(const bf16x8*)(
                &Rt_s[(mt * 16 + r16) * RT_STRIDE + kh * 32 + q4 * 8]);
    __syncthreads();                 // snc visible

    unsigned short* xw = &xs[w * 16 * RT_STRIDE];

    #pragma unroll
    for (int nt = 0; nt < 2; ++nt) {
        const size_t row0 = (size_t)(hv_base + w * 32 + nt * 16);

        // load 16 rows (4KiB) wave-contiguous, cvt bf16, stage wave-private
        {
            const float4* xg = (const float4*)(x + row0 * H_DIM);
            #pragma unroll
            for (int i = 0; i < 4; ++i) {
                const int flat = i * 64 + l;     // float4 chunk 0..255
                const float4 v = xg[flat];
                const int row = flat >> 4;       // 0..15
                const int c4  = flat & 15;
                ushort4 b;
                b.x = f2bf(v.x); b.y = f2bf(v.y);
                b.z = f2bf(v.z); b.w = f2bf(v.w);
                *(ushort4*)(&xw[row * RT_STRIDE + c4 * 4]) = b;
            }
        }

        // B frags + MFMA (wave-private; lgkmcnt ordering)
        f32x4 acc[4];
        {
            bf16x8 b0 = *(const bf16x8*)(&xw[r16 * RT_STRIDE + 0 * 32 + q4 * 8]);
            bf16x8 b1 = *(const bf16x8*)(&xw[r16 * RT_STRIDE + 1 * 32 + q4 * 8]);
            #pragma unroll
            for (int mt = 0; mt < 4; ++mt) {
                f32x4 z = {0.0f, 0.0f, 0.0f, 0.0f};
                z = __builtin_amdgcn_mfma_f32_16x16x32_bf16(afr[mt][0], b0, z, 0, 0, 0);
                z = __builtin_amdgcn_mfma_f32_16x16x32_bf16(afr[mt][1], b1, z, 0, 0, 0);
                acc[mt] = z;
            }
        }

        // RoPE in-register (acc tiles 0,1 = x1; 2,3 = x2), direct float4 stores
        const int pl = w * 2 + nt;
        float* op = out + row0 * H_DIM + (size_t)r16 * H_DIM;

        #pragma unroll
        for (int half = 0; half < 2; ++half) {
            const int p0 = half * 16 + q4 * 4;           // 4 consecutive cols
            const float4 sn = *(const float4*)(&snc[pl * 64 + p0]);
            const float4 cs = *(const float4*)(&snc[pl * 64 + 32 + p0]);
            const f32x4 a1 = acc[half];
            const f32x4 a2 = acc[half + 2];
            float4 olo, ohi;
            olo.x = a1.x * cs.x - a2.x * sn.x;
            olo.y = a1.y * cs.y - a2.y * sn.y;
            olo.z = a1.z * cs.z - a2.z * sn.z;
            olo.w = a1.w * cs.w - a2.w * sn.w;
            ohi.x = a1.x * sn.x + a2.x * cs.x;
            ohi.y = a1.y * sn.y + a2.y * cs.y;
            ohi.z = a1.z * sn.z + a2.z * cs.z;
            ohi.w = a1.w * sn.w + a2.w * cs.w;
            *(float4*)(op + p0)      = olo;
            *(float4*)(op + 32 + p0) = ohi;
        }
    }
}

// ---------------------------------------------------------------------------
extern "C" void kernel_launch(void* const* d_in, const int* in_sizes, int n_in,
                              void* d_out, int out_size, void* d_ws, size_t ws_size,
                              hipStream_t stream)
{
    const float* x      = (const float*)d_in[0];
    const float* thetas = (const float*)d_in[1];
    const float* pairs  = (const float*)d_in[2];
    const float* tscale = (const float*)d_in[3];
    const float* M      = (const float*)d_in[4];
    const float* invf   = (const float*)d_in[5];
    float* out = (float*)d_out;

    const int n_hv   = in_sizes[0] / H_DIM;     // B*S*N_HEAD = 262144
    const int blocks = n_hv / HVPB;             // 2048
    rope_fused_kernel<<<blocks, 256, 0, stream>>>(x, thetas, pairs, tscale,
                                                  M, invf, out);
}

// Round 8
// 28.416 us; speedup vs baseline: 1.2312x; 1.1547x over previous
//
#include <hip/hip_runtime.h>
#include <hip/hip_bf16.h>
#include <math.h>

// Problem constants (fixed by the reference's setup_inputs)
#define N_STATE 1024
#define N_HEAD  16
#define H_DIM   64          // N_STATE / N_HEAD
#define NUM_ROT 8
#define SEQ     4096
#define HVPB    128         // head-vectors per tile
#define TILES   2           // tiles per block

typedef __attribute__((ext_vector_type(8))) short bf16x8;
typedef __attribute__((ext_vector_type(4))) float f32x4;

// float -> bf16 (round-to-nearest-even)
__device__ __forceinline__ unsigned short f2bf(float f) {
    union { float f; unsigned u; } v; v.f = f;
    unsigned r = v.u + 0x7fffu + ((v.u >> 16) & 1u);
    return (unsigned short)(r >> 16);
}

#define RF_STRIDE 68   // floats per row of Rf (64 + 4 pad; 272B, 16B-aligned)
#define RT_STRIDE 72   // shorts per row of Rt_s / xs (144B, 16B-aligned)
// Static LDS layout (bytes):
//   [0     , 17408) Rf f32[64][68] (compose only)
//                   overlay after compose: snc f32[2][8][64] at [0,4096)
//                                          xs  bf16 4 waves x [16][72] at [4096,13312)
//   [17408 , 26624) Rt_s bf16[64][72]  permuted R^T, live whole kernel
//   [26624 , 26688) csh: 8 x (cos,sin)
//   [26688 , 26752) prs: 16 ints
#define SM_TOTAL 26752

// ---------------------------------------------------------------------------
// Fused persistent kernel: per-block redundant compose (A) + 2 tiles of the
// main transform (B) with one-chunk-lookahead x prefetch.
// ---------------------------------------------------------------------------
__global__ __launch_bounds__(256, 4)
void rope_fused_kernel(const float* __restrict__ x,
                       const float* __restrict__ thetas,
                       const float* __restrict__ pairs,
                       const float* __restrict__ theta_scale,
                       const float* __restrict__ M,
                       const float* __restrict__ inv_freq,
                       float* __restrict__ out,
                       int nb)                       // blocks in grid
{
    __shared__ __align__(16) char smem[SM_TOTAL];
    float*          Rf   = (float*)(smem);
    unsigned short* Rt_s = (unsigned short*)(smem + 17408);
    float*          csh  = (float*)(smem + 26624);
    int*            prs  = (int*)(smem + 26688);
    float*          snc  = (float*)(smem);                    // overlay
    unsigned short* xs   = (unsigned short*)(smem + 4096);    // overlay

    const int t   = threadIdx.x;
    const int w   = t >> 6;
    const int l   = t & 63;
    const int r16 = l & 15;
    const int q4  = l >> 4;
    const int bid = blockIdx.x;

    // ===================== phase A: compose =====================
    // 0) issue M reads for compose A-frags NOW (L2-hot; latency hides under
    //    zeroing/params/Givens).  am[kh][e] = M[k2][f], k2=kh*32+q4*8+e, f=w*16+r16
    float am[2][8];
    #pragma unroll
    for (int kh = 0; kh < 2; ++kh)
        #pragma unroll
        for (int e = 0; e < 8; ++e)
            am[kh][e] = M[(kh * 32 + q4 * 8 + e) * H_DIM + w * 16 + r16];

    // small params
    if (t < NUM_ROT) {
        float sv, cv;
        sincosf(thetas[t] * theta_scale[0], &sv, &cv);
        csh[2 * t] = cv; csh[2 * t + 1] = sv;
    }
    if (t < 2 * NUM_ROT) prs[t] = (int)pairs[t];
    // zero Rf (4352 floats = 17/thread)
    #pragma unroll
    for (int q = 0; q < 17; ++q) Rf[t + q * 256] = 0.0f;
    __syncthreads();

    // Givens rotations as column ops — row-local => barrier-free loop
    if (t < H_DIM) {
        float* myrow = &Rf[t * RF_STRIDE];
        myrow[t] = 1.0f;
        #pragma unroll
        for (int k = 0; k < NUM_ROT; ++k) {
            const int   i = prs[2 * k], j = prs[2 * k + 1];
            const float c = csh[2 * k], s = csh[2 * k + 1];
            const float ri = myrow[i], rj = myrow[j];
            if (i == j) {
                myrow[i] = c * ri;                    // chained .at corner case
            } else {
                myrow[i] =  c * ri + s * rj;
                myrow[j] = -s * ri + c * rj;
            }
        }
    }
    __syncthreads();

    // compose-GEMM on matrix pipe: D = M^T(A) x R^T(B) = final^T
    {
        bf16x8 ca[2];
        #pragma unroll
        for (int kh = 0; kh < 2; ++kh) {
            bf16x8 a;
            #pragma unroll
            for (int e = 0; e < 8; ++e) a[e] = (short)f2bf(am[kh][e]);
            ca[kh] = a;
        }
        f32x4 dacc[4];
        #pragma unroll
        for (int j = 0; j < 4; ++j) {
            f32x4 z = {0.f, 0.f, 0.f, 0.f};
            #pragma unroll
            for (int kh = 0; kh < 2; ++kh) {
                const float* rp = &Rf[(j * 16 + r16) * RF_STRIDE + kh * 32 + q4 * 8];
                const float4 f0 = *(const float4*)(rp);
                const float4 f1 = *(const float4*)(rp + 4);
                bf16x8 b;
                b[0] = (short)f2bf(f0.x); b[1] = (short)f2bf(f0.y);
                b[2] = (short)f2bf(f0.z); b[3] = (short)f2bf(f0.w);
                b[4] = (short)f2bf(f1.x); b[5] = (short)f2bf(f1.y);
                b[6] = (short)f2bf(f1.z); b[7] = (short)f2bf(f1.w);
                z = __builtin_amdgcn_mfma_f32_16x16x32_bf16(ca[kh], b, z, 0, 0, 0);
            }
            dacc[j] = z;
        }
        // D[f][k] -> Rt_s[p][k], p = (f&1)*32 + f>>1  ([evens|odds] perm)
        #pragma unroll
        for (int j = 0; j < 4; ++j) {
            #pragma unroll
            for (int r = 0; r < 4; ++r) {
                const int f = w * 16 + q4 * 4 + r;       // C/D layout row
                const int p = ((f & 1) << 5) | (f >> 1);
                Rt_s[p * RT_STRIDE + j * 16 + r16] = f2bf(dacc[j][r]);
            }
        }
    }

    // sin/cos for BOTH tiles in regs before the overlay barrier
    const int srl = t >> 5;          // 0..7
    const int sf  = t & 31;          // 0..31
    float svv[TILES], cvv[TILES];
    {
        const float fr = inv_freq[sf];
        #pragma unroll
        for (int tt = 0; tt < TILES; ++tt) {
            const int pos = ((bid + tt * nb) * 8 + srl) & (SEQ - 1);
            sincosf((float)pos * fr, &svv[tt], &cvv[tt]);
        }
    }
    __syncthreads();                 // Rt_s complete; Rf dead => overlay ok

    // ===================== phase B =====================
    #pragma unroll
    for (int tt = 0; tt < TILES; ++tt) {
        snc[tt * 512 + srl * 64 + sf]      = svv[tt];
        snc[tt * 512 + srl * 64 + 32 + sf] = cvv[tt];
    }
    // A-frags from Rt_s (written pre-barrier)
    bf16x8 afr[4][2];
    #pragma unroll
    for (int mt = 0; mt < 4; ++mt)
        #pragma unroll
        for (int kh = 0; kh < 2; ++kh)
            afr[mt][kh] = *(const bf16x8*)(
                &Rt_s[(mt * 16 + r16) * RT_STRIDE + kh * 32 + q4 * 8]);
    __syncthreads();                 // snc visible

    unsigned short* xw = &xs[w * 16 * RT_STRIDE];

    // 4 chunks = (tile, nt); one-chunk-lookahead prefetch
    float4 cur[4], nxt[4];
    {   // load chunk 0
        const size_t row0 = (size_t)bid * HVPB + w * 32;
        const float4* xg = (const float4*)(x + row0 * H_DIM);
        #pragma unroll
        for (int i = 0; i < 4; ++i) cur[i] = xg[i * 64 + l];
    }

    #pragma unroll
    for (int c = 0; c < 2 * TILES; ++c) {
        const int tt = c >> 1, nt = c & 1;
        const size_t row0 = (size_t)(bid + tt * nb) * HVPB + w * 32 + nt * 16;

        // prefetch next chunk
        if (c + 1 < 2 * TILES) {
            const int tt2 = (c + 1) >> 1, nt2 = (c + 1) & 1;
            const size_t r2 = (size_t)(bid + tt2 * nb) * HVPB + w * 32 + nt2 * 16;
            const float4* xg = (const float4*)(x + r2 * H_DIM);
            #pragma unroll
            for (int i = 0; i < 4; ++i) nxt[i] = xg[i * 64 + l];
        }

        // cvt + stage (wave-private; lgkmcnt ordering)
        #pragma unroll
        for (int i = 0; i < 4; ++i) {
            const int flat = i * 64 + l;
            const int row = flat >> 4, c4 = flat & 15;
            ushort4 b;
            b.x = f2bf(cur[i].x); b.y = f2bf(cur[i].y);
            b.z = f2bf(cur[i].z); b.w = f2bf(cur[i].w);
            *(ushort4*)(&xw[row * RT_STRIDE + c4 * 4]) = b;
        }

        // B frags + MFMA
        f32x4 acc[4];
        {
            bf16x8 b0 = *(const bf16x8*)(&xw[r16 * RT_STRIDE + q4 * 8]);
            bf16x8 b1 = *(const bf16x8*)(&xw[r16 * RT_STRIDE + 32 + q4 * 8]);
            #pragma unroll
            for (int mt = 0; mt < 4; ++mt) {
                f32x4 z = {0.0f, 0.0f, 0.0f, 0.0f};
                z = __builtin_amdgcn_mfma_f32_16x16x32_bf16(afr[mt][0], b0, z, 0, 0, 0);
                z = __builtin_amdgcn_mfma_f32_16x16x32_bf16(afr[mt][1], b1, z, 0, 0, 0);
                acc[mt] = z;
            }
        }

        // RoPE in-register; direct full-line float4 stores
        const int pl = tt * 512 + (w * 2 + nt) * 64;
        float* op = out + row0 * H_DIM + (size_t)r16 * H_DIM;
        #pragma unroll
        for (int half = 0; half < 2; ++half) {
            const int p0 = half * 16 + q4 * 4;
            const float4 sn = *(const float4*)(&snc[pl + p0]);
            const float4 cs = *(const float4*)(&snc[pl + 32 + p0]);
            const f32x4 a1 = acc[half];
            const f32x4 a2 = acc[half + 2];
            float4 olo, ohi;
            olo.x = a1.x * cs.x - a2.x * sn.x;
            olo.y = a1.y * cs.y - a2.y * sn.y;
            olo.z = a1.z * cs.z - a2.z * sn.z;
            olo.w = a1.w * cs.w - a2.w * sn.w;
            ohi.x = a1.x * sn.x + a2.x * cs.x;
            ohi.y = a1.y * sn.y + a2.y * cs.y;
            ohi.z = a1.z * sn.z + a2.z * cs.z;
            ohi.w = a1.w * sn.w + a2.w * cs.w;
            *(float4*)(op + p0)      = olo;
            *(float4*)(op + 32 + p0) = ohi;
        }

        // rotate prefetch buffer
        if (c + 1 < 2 * TILES) {
            #pragma unroll
            for (int i = 0; i < 4; ++i) cur[i] = nxt[i];
        }
    }
}

// ---------------------------------------------------------------------------
extern "C" void kernel_launch(void* const* d_in, const int* in_sizes, int n_in,
                              void* d_out, int out_size, void* d_ws, size_t ws_size,
                              hipStream_t stream)
{
    const float* x      = (const float*)d_in[0];
    const float* thetas = (const float*)d_in[1];
    const float* pairs  = (const float*)d_in[2];
    const float* tscale = (const float*)d_in[3];
    const float* M      = (const float*)d_in[4];
    const float* invf   = (const float*)d_in[5];
    float* out = (float*)d_out;

    const int n_hv   = in_sizes[0] / H_DIM;          // B*S*N_HEAD = 262144
    const int blocks = n_hv / (HVPB * TILES);        // 1024
    rope_fused_kernel<<<blocks, 256, 0, stream>>>(x, thetas, pairs, tscale,
                                                  M, invf, out, blocks);
}